// Round 14
// baseline (1141.316 us; speedup 1.0000x reference)
//
#include <hip/hip_runtime.h>

#define BB 8
#define NN 2048
#define WGS 1024
#define GRID 512                  // 2 WGs/CU (resource-guaranteed) -> 32/32 waves
#define WG_PER_B (GRID / BB)      // 64 WGs per batch
#define ROWS_WG (NN / WG_PER_B)   // 32 rows per WG
#define NWAVES (WGS / 64)         // 16
#define RPW (ROWS_WG / NWAVES)    // 2 rows per wave
#define CHUNKS (NN / 64)          // 32
#define MAX_ITER 50

// eps = 0.005; log2 domain: SCL = log2(e)/eps
constexpr float SCL       = 288.5390081777927f;
constexpr float LN2f      = 0.6931471805599453f;
constexpr float EPSf      = 0.005f;
constexpr float EPS_LOGMU = -0.03812309493079699f; // 0.005 * (-ln 2048)

#define SCOPE __HIP_MEMORY_SCOPE_AGENT

__device__ __forceinline__ float aloadf(const float* p){return __hip_atomic_load(p,__ATOMIC_RELAXED,SCOPE);}
__device__ __forceinline__ void  astoref(float* p,float v){__hip_atomic_store(p,v,__ATOMIC_RELAXED,SCOPE);}
__device__ __forceinline__ int   aloadi(const int* p){return __hip_atomic_load(p,__ATOMIC_RELAXED,SCOPE);}

__device__ __forceinline__ float fexp2(float x){return __builtin_amdgcn_exp2f(x);}
__device__ __forceinline__ float flog2(float x){return __builtin_amdgcn_logf(x);}

// monotone float<->int map so atomicMax(int) orders floats
__device__ __forceinline__ int   fkey(float x){int i=__float_as_int(x);return i>=0?i:i^0x7fffffff;}
__device__ __forceinline__ float funkey(int k){return __int_as_float(k>=0?k:k^0x7fffffff);}

__device__ __forceinline__ float wsum(float v){
  #pragma unroll
  for (int d = 32; d; d >>= 1) v += __shfl_xor(v, d, 64);
  return v;
}

// SINGLE-USE monotonic barrier (r12, proven): arrive = atomicAdd, release =
// cnt==nwg. No reset/generation -> reuse/ABA races structurally impossible.
// Plain (non-coop) launch: co-residency of all 512 WGs is guaranteed by
// resource arithmetic (65KB LDS, 36 VGPR, 2048thr/CU); if that ever fails,
// the deadman (~33ms/barrier max) yields a fast wrong answer, not a hang.
__device__ __forceinline__ void sbar(int* cnt, int nwg){
  __syncthreads();
  if (threadIdx.x == 0) {
    asm volatile("s_waitcnt vmcnt(0)" ::: "memory");
    __hip_atomic_fetch_add(cnt, 1, __ATOMIC_RELAXED, SCOPE);
    int spins = 0;
    while (aloadi(cnt) < nwg) {
      __builtin_amdgcn_s_sleep(2);
      if (++spins > (1 << 17)) break;   // deadman
    }
  }
  __syncthreads();
}

// One-time prep: pack {x,y,z,|p|^2} for both clouds; zero 801 single-use
// barrier counters; set 800 max-slots to -inf; zero accum.
__global__ __launch_bounds__(256) void pack_pts(
    const float* __restrict__ pcs1, const float* __restrict__ pcs2,
    float4* __restrict__ rp1, float4* __restrict__ rp2,
    int* __restrict__ cntArr, int* __restrict__ slotMF,
    int* __restrict__ slotMG, float* __restrict__ accum)
{
  int idx = blockIdx.x * 256 + threadIdx.x;
  if (idx == 0) *accum = 0.f;
  if (idx < 801) cntArr[idx * 16] = 0;
  if (idx >= 2048 && idx < 2448) slotMF[(idx - 2048) * 16] = fkey(-3.0e38f);
  if (idx >= 4096 && idx < 4496) slotMG[(idx - 4096) * 16] = fkey(-3.0e38f);
  if (idx >= 2 * BB * NN) return;
  if (idx < BB * NN) {
    const float* s = pcs1 + 3 * (size_t)idx;
    float x = s[0], y = s[1], z = s[2];
    rp1[idx] = make_float4(x, y, z, fmaf(x, x, fmaf(y, y, z * z)));
  } else {
    int j = idx - BB * NN;
    const float* s = pcs2 + 3 * (size_t)j;
    float x = s[0], y = s[1], z = s[2];
    rp2[j] = make_float4(x, y, z, fmaf(x, x, fmaf(y, y, z * z)));
  }
}

// One half-iteration phase (r12's proven single-pass form, 2 rows/wave).
// J[j].w = (pot_j - qq_j)*SCL - M ; exponent <= 0 since M >= max_j pot_j*SCL.
// potIn/potOut accessed ONLY via sc1 atomics.
__device__ __forceinline__ void half_phase(
    float4* __restrict__ J, float* __restrict__ red,
    const float4* __restrict__ RP, const float4* __restrict__ CP,
    const float* __restrict__ potIn, float* __restrict__ potOut,
    float M, int* __restrict__ slotOut,
    int b, int sub, int tid, int lane, int wv, bool zero)
{
  const size_t bo = (size_t)b * NN;
  for (int j = tid; j < NN; j += WGS) {
    float4 q = CP[bo + j];                       // plain: pack_pts output
    float pot = zero ? 0.f : aloadf(potIn + bo + j);
    J[j] = make_float4(q.x, q.y, q.z, fmaf(pot - q.w, SCL, -M));
  }
  __syncthreads();

  const int i0 = sub * ROWS_WG + wv * RPW;
  const float4 p0 = RP[bo + i0], p1 = RP[bo + i0 + 1];
  const float X0x=2.f*SCL*p0.x, X0y=2.f*SCL*p0.y, X0z=2.f*SCL*p0.z, B0=-SCL*p0.w;
  const float X1x=2.f*SCL*p1.x, X1y=2.f*SCL*p1.y, X1z=2.f*SCL*p1.z, B1=-SCL*p1.w;

  // unroll capped at 4: full unroll clusters 32 b128 loads -> spill (r1..r5)
  float s0 = 0.f, s1 = 0.f;
  #pragma unroll 4
  for (int k = 0; k < CHUNKS; ++k) {
    float4 q = J[k * 64 + lane];
    s0 += fexp2(fmaf(X0x, q.x, fmaf(X0y, q.y, fmaf(X0z, q.z, q.w + B0))));
    s1 += fexp2(fmaf(X1x, q.x, fmaf(X1y, q.y, fmaf(X1z, q.z, q.w + B1))));
  }
  const float S0 = wsum(s0), S1 = wsum(s1);
  if (lane == 0) {
    const float o0 = EPS_LOGMU - EPSf*LN2f*(M + flog2(fmaxf(S0, 1e-37f)));
    const float o1 = EPS_LOGMU - EPSf*LN2f*(M + flog2(fmaxf(S1, 1e-37f)));
    astoref(potOut + bo + i0 + 0, o0);
    astoref(potOut + bo + i0 + 1, o1);
    red[wv] = fmaxf(o0, o1);
  }
  __syncthreads();
  if (tid == 0) {
    float mx = red[0];
    #pragma unroll
    for (int w = 1; w < NWAVES; ++w) mx = fmaxf(mx, red[w]);
    atomicMax(slotOut, fkey(mx));
  }
}

__global__ __launch_bounds__(WGS) void emd_sinkhorn_fused(
    const float4* __restrict__ P1r, const float4* __restrict__ P2r,
    float* __restrict__ fArr, float* __restrict__ gArr,
    int* __restrict__ cntArr, int* __restrict__ slotMF,
    int* __restrict__ slotMG, float* __restrict__ accum,
    float* __restrict__ out)
{
  __shared__ float4 J[NN];
  __shared__ float red[NWAVES];
  const int wg = blockIdx.x, tid = threadIdx.x;
  const int b = wg / WG_PER_B, sub = wg % WG_PER_B;
  const int lane = tid & 63, wv = tid >> 6;
  const size_t bo = (size_t)b * NN;

  for (int t = 0; t < MAX_ITER; ++t) {
    // f-update: rows=pcs1, cols=pcs2+g ; M from last g-phase (0 at t=0)
    const float Mf = (t == 0) ? 0.f
        : funkey(aloadi(slotMG + ((t - 1) * 8 + b) * 16)) * SCL;
    half_phase(J, red, P1r, P2r, gArr, fArr, Mf,
               slotMF + (t * 8 + b) * 16, b, sub, tid, lane, wv, t == 0);
    sbar(cntArr + ((2 * t) * 8 + b) * 16, WG_PER_B);

    // g-update: rows=pcs2, cols=pcs1+f ; M from this f-phase
    const float Mg = funkey(aloadi(slotMF + (t * 8 + b) * 16)) * SCL;
    half_phase(J, red, P2r, P1r, fArr, gArr, Mg,
               slotMG + (t * 8 + b) * 16, b, sub, tid, lane, wv, false);
    sbar(cntArr + ((2 * t + 1) * 8 + b) * 16, WG_PER_B);
  }

  // finalize: dist_i = N * sum_j exp2((f_i+g_j-C_ij)*SCL) * C_ij
  for (int j = tid; j < NN; j += WGS) {
    float4 q = P2r[bo + j];
    J[j] = make_float4(q.x, q.y, q.z, aloadf(gArr + bo + j) * SCL);
  }
  __syncthreads();

  const int i0 = sub * ROWS_WG + wv * RPW;
  float part = 0.f;
  #pragma unroll 1
  for (int r = 0; r < RPW; ++r) {
    const int i = i0 + r;
    const float4 p = P1r[bo + i];
    const float Fi = aloadf(fArr + bo + i) * SCL;
    float a0 = 0.f, a1 = 0.f;
    #pragma unroll 2
    for (int k = 0; k < CHUNKS; k += 2) {
      float4 qa = J[k * 64 + lane];
      float4 qb = J[(k + 1) * 64 + lane];
      float dxa = p.x - qa.x, dya = p.y - qa.y, dza = p.z - qa.z;
      float ca = fmaf(dxa, dxa, fmaf(dya, dya, dza * dza));
      a0 = fmaf(fexp2(fmaf(-SCL, ca, Fi + qa.w)), ca, a0);
      float dxb = p.x - qb.x, dyb = p.y - qb.y, dzb = p.z - qb.z;
      float cb = fmaf(dxb, dxb, fmaf(dyb, dyb, dzb * dzb));
      a1 = fmaf(fexp2(fmaf(-SCL, cb, Fi + qb.w)), cb, a1);
    }
    float lacc = wsum(a0 + a1);
    if (lane == 0) part += sqrtf((float)NN * lacc + 1e-12f);
  }
  if (lane == 0) red[wv] = part;
  __syncthreads();
  if (tid == 0) {
    float s = 0.f;
    #pragma unroll
    for (int w = 0; w < NWAVES; ++w) s += red[w];
    atomicAdd(accum, s);
  }
  sbar(cntArr + 800 * 16, GRID);               // global: all partials landed
  if (wg == 0 && tid == 0) out[0] = aloadf(accum) * (1.f / 16384.f);
}

extern "C" void kernel_launch(void* const* d_in, const int* in_sizes, int n_in,
                              void* d_out, int out_size, void* d_ws, size_t ws_size,
                              hipStream_t stream) {
  const float* pcs1 = (const float*)d_in[0];
  const float* pcs2 = (const float*)d_in[1];
  float* out = (float*)d_out;
  char*  base = (char*)d_ws;
  float* fArr   = (float*)base;                    // 64KB
  float* gArr   = (float*)(base + 64 * 1024);      // 64KB
  float* accum  = (float*)(base + 128 * 1024);     // 1 float
  int*   cntArr = (int*)(base + 192 * 1024);       // 801 x 64B
  int*   slotMF = (int*)(base + 256 * 1024);       // 400 x 64B
  int*   slotMG = (int*)(base + 320 * 1024);       // 400 x 64B
  float4* P1r   = (float4*)(base + 512 * 1024);    // 256KB
  float4* P2r   = (float4*)(base + 768 * 1024);    // 256KB

  pack_pts<<<(2 * BB * NN + 255) / 256, 256, 0, stream>>>(
      pcs1, pcs2, P1r, P2r, cntArr, slotMF, slotMG, accum);

  // PLAIN launch (not cooperative): the coop API caps 1024-thr grids at 256
  // blocks on this runtime (r13: silent no-op launch). Co-residency of 512
  // WGs is resource-guaranteed; the barrier + deadman handle the rest.
  emd_sinkhorn_fused<<<GRID, WGS, 0, stream>>>(
      P1r, P2r, fArr, gArr, cntArr, slotMF, slotMG, accum, out);
}

// Round 15
// 978.043 us; speedup vs baseline: 1.1669x; 1.1669x over previous
//
#include <hip/hip_runtime.h>

#define BB 8
#define NN 2048
#define WGS 1024
#define GRID 256
#define WG_PER_B (GRID / BB)      // 32 WGs per batch
#define ROWS_WG (NN / WG_PER_B)   // 64 rows per WG
#define NWAVES (WGS / 64)         // 16
#define RPW (ROWS_WG / NWAVES)    // 4 rows per wave
#define CHUNKS (NN / 64)          // 32
#define MAX_ITER 50

// eps = 0.005; log2 domain: SCL = log2(e)/eps
constexpr float SCL       = 288.5390081777927f;
constexpr float LN2f      = 0.6931471805599453f;
constexpr float EPSf      = 0.005f;
constexpr float EPS_LOGMU = -0.03812309493079699f; // 0.005 * (-ln 2048)

#define SCOPE __HIP_MEMORY_SCOPE_AGENT

__device__ __forceinline__ float aloadf(const float* p){return __hip_atomic_load(p,__ATOMIC_RELAXED,SCOPE);}
__device__ __forceinline__ void  astoref(float* p,float v){__hip_atomic_store(p,v,__ATOMIC_RELAXED,SCOPE);}
__device__ __forceinline__ int   aloadi(const int* p){return __hip_atomic_load(p,__ATOMIC_RELAXED,SCOPE);}

__device__ __forceinline__ float fexp2(float x){return __builtin_amdgcn_exp2f(x);}
__device__ __forceinline__ float flog2(float x){return __builtin_amdgcn_logf(x);}

__device__ __forceinline__ float wsum(float v){
  #pragma unroll
  for (int d = 32; d; d >>= 1) v += __shfl_xor(v, d, 64);
  return v;
}

// SINGLE-USE monotonic barrier (r12/r14 proven): arrive = atomicAdd,
// release = cnt==nwg. No reset/generation -> no reuse/ABA races. Deadman
// converts any deadlock into a fast wrong answer, never a 600s hang.
__device__ __forceinline__ void sbar(int* cnt, int nwg){
  __syncthreads();
  if (threadIdx.x == 0) {
    asm volatile("s_waitcnt vmcnt(0)" ::: "memory");
    __hip_atomic_fetch_add(cnt, 1, __ATOMIC_RELAXED, SCOPE);
    int spins = 0;
    while (aloadi(cnt) < nwg) {
      __builtin_amdgcn_s_sleep(1);
      if (++spins > (1 << 17)) break;   // deadman
    }
  }
  __syncthreads();
}

// One-time prep: pack {x,y,z,|p|^2} for both clouds; zero 801 single-use
// barrier counters; zero accum. (No max-slots: the M-shift is gone — see
// half_phase numerics note.)
__global__ __launch_bounds__(256) void pack_pts(
    const float* __restrict__ pcs1, const float* __restrict__ pcs2,
    float4* __restrict__ rp1, float4* __restrict__ rp2,
    int* __restrict__ cntArr, float* __restrict__ accum)
{
  int idx = blockIdx.x * 256 + threadIdx.x;
  if (idx == 0) *accum = 0.f;
  if (idx < 801) cntArr[idx * 16] = 0;
  if (idx >= 2 * BB * NN) return;
  if (idx < BB * NN) {
    const float* s = pcs1 + 3 * (size_t)idx;
    float x = s[0], y = s[1], z = s[2];
    rp1[idx] = make_float4(x, y, z, fmaf(x, x, fmaf(y, y, z * z)));
  } else {
    int j = idx - BB * NN;
    const float* s = pcs2 + 3 * (size_t)j;
    float x = s[0], y = s[1], z = s[2];
    rp2[j] = make_float4(x, y, z, fmaf(x, x, fmaf(y, y, z * z)));
  }
}

// One half-iteration phase, NO max-shift. Numerics: potentials stay within
// [-0.1,0.1] (|pot| <= eps*logN + C_NN by the Sinkhorn update), so exp2 args
// span [+15,-890]; sub-2^-126 terms flush to 0 but the row sum's largest
// term is >= 2^-43 (nearest-neighbor bound) -> relative error < 2^-80.
// fmaxf(S,1e-37) backstops. Removing M deletes a far slot-load at phase
// start and a far atomicMax + LDS reduction + syncthreads at phase end —
// all serial critical-path latency. pot I/O via sc1 atomics only.
__device__ __forceinline__ void half_phase(
    float4* __restrict__ J,
    const float4* __restrict__ RP, const float4* __restrict__ CP,
    const float* __restrict__ potIn, float* __restrict__ potOut,
    int b, int sub, int tid, int lane, int wv, bool zero)
{
  const size_t bo = (size_t)b * NN;
  for (int j = tid; j < NN; j += WGS) {
    float4 q = CP[bo + j];                       // plain: pack_pts output
    float pot = zero ? 0.f : aloadf(potIn + bo + j);
    J[j] = make_float4(q.x, q.y, q.z, (pot - q.w) * SCL);
  }
  __syncthreads();

  const int i0 = sub * ROWS_WG + wv * RPW;
  const float4 p0 = RP[bo+i0], p1 = RP[bo+i0+1], p2 = RP[bo+i0+2], p3 = RP[bo+i0+3];
  const float X0x=2.f*SCL*p0.x, X0y=2.f*SCL*p0.y, X0z=2.f*SCL*p0.z, B0=-SCL*p0.w;
  const float X1x=2.f*SCL*p1.x, X1y=2.f*SCL*p1.y, X1z=2.f*SCL*p1.z, B1=-SCL*p1.w;
  const float X2x=2.f*SCL*p2.x, X2y=2.f*SCL*p2.y, X2z=2.f*SCL*p2.z, B2=-SCL*p2.w;
  const float X3x=2.f*SCL*p3.x, X3y=2.f*SCL*p3.y, X3z=2.f*SCL*p3.z, B3=-SCL*p3.w;

  // unroll capped at 4: full unroll clusters 32 b128 loads -> spill (r1..r5)
  float s0 = 0.f, s1 = 0.f, s2 = 0.f, s3 = 0.f;
  #pragma unroll 4
  for (int k = 0; k < CHUNKS; ++k) {
    float4 q = J[k * 64 + lane];
    s0 += fexp2(fmaf(X0x, q.x, fmaf(X0y, q.y, fmaf(X0z, q.z, q.w + B0))));
    s1 += fexp2(fmaf(X1x, q.x, fmaf(X1y, q.y, fmaf(X1z, q.z, q.w + B1))));
    s2 += fexp2(fmaf(X2x, q.x, fmaf(X2y, q.y, fmaf(X2z, q.z, q.w + B2))));
    s3 += fexp2(fmaf(X3x, q.x, fmaf(X3y, q.y, fmaf(X3z, q.z, q.w + B3))));
  }
  const float S0 = wsum(s0), S1 = wsum(s1), S2 = wsum(s2), S3 = wsum(s3);
  // compute all 4 outputs in every lane (cheap), store via lanes 0..3 in
  // parallel instead of 4 serial stores on lane 0
  const float o0 = EPS_LOGMU - EPSf*LN2f*flog2(fmaxf(S0, 1e-37f));
  const float o1 = EPS_LOGMU - EPSf*LN2f*flog2(fmaxf(S1, 1e-37f));
  const float o2 = EPS_LOGMU - EPSf*LN2f*flog2(fmaxf(S2, 1e-37f));
  const float o3 = EPS_LOGMU - EPSf*LN2f*flog2(fmaxf(S3, 1e-37f));
  const float oo = lane == 0 ? o0 : (lane == 1 ? o1 : (lane == 2 ? o2 : o3));
  if (lane < 4) astoref(potOut + bo + i0 + lane, oo);
}

__global__ __launch_bounds__(WGS) void emd_sinkhorn_fused(
    const float4* __restrict__ P1r, const float4* __restrict__ P2r,
    float* __restrict__ fArr, float* __restrict__ gArr,
    int* __restrict__ cntArr, float* __restrict__ accum,
    float* __restrict__ out)
{
  __shared__ float4 J[NN];
  __shared__ float red[NWAVES];
  const int wg = blockIdx.x, tid = threadIdx.x;
  const int b = wg / WG_PER_B, sub = wg % WG_PER_B;
  const int lane = tid & 63, wv = tid >> 6;
  const size_t bo = (size_t)b * NN;

  for (int t = 0; t < MAX_ITER; ++t) {
    // f-update: rows=pcs1, cols=pcs2+g (g==0 at t=0)
    half_phase(J, P1r, P2r, gArr, fArr, b, sub, tid, lane, wv, t == 0);
    sbar(cntArr + ((2 * t) * 8 + b) * 16, WG_PER_B);
    // g-update: rows=pcs2, cols=pcs1+f
    half_phase(J, P2r, P1r, fArr, gArr, b, sub, tid, lane, wv, false);
    sbar(cntArr + ((2 * t + 1) * 8 + b) * 16, WG_PER_B);
  }

  // finalize: dist_i = N * sum_j exp2((f_i+g_j-C_ij)*SCL) * C_ij
  for (int j = tid; j < NN; j += WGS) {
    float4 q = P2r[bo + j];
    J[j] = make_float4(q.x, q.y, q.z, aloadf(gArr + bo + j) * SCL);
  }
  __syncthreads();

  const int i0 = sub * ROWS_WG + wv * RPW;
  float part = 0.f;
  #pragma unroll 1
  for (int r = 0; r < RPW; ++r) {
    const int i = i0 + r;
    const float4 p = P1r[bo + i];
    const float Fi = aloadf(fArr + bo + i) * SCL;
    float a0 = 0.f, a1 = 0.f;
    #pragma unroll 2
    for (int k = 0; k < CHUNKS; k += 2) {
      float4 qa = J[k * 64 + lane];
      float4 qb = J[(k + 1) * 64 + lane];
      float dxa = p.x - qa.x, dya = p.y - qa.y, dza = p.z - qa.z;
      float ca = fmaf(dxa, dxa, fmaf(dya, dya, dza * dza));
      a0 = fmaf(fexp2(fmaf(-SCL, ca, Fi + qa.w)), ca, a0);
      float dxb = p.x - qb.x, dyb = p.y - qb.y, dzb = p.z - qb.z;
      float cb = fmaf(dxb, dxb, fmaf(dyb, dyb, dzb * dzb));
      a1 = fmaf(fexp2(fmaf(-SCL, cb, Fi + qb.w)), cb, a1);
    }
    float lacc = wsum(a0 + a1);
    if (lane == 0) part += sqrtf((float)NN * lacc + 1e-12f);
  }
  if (lane == 0) red[wv] = part;
  __syncthreads();
  if (tid == 0) {
    float s = 0.f;
    #pragma unroll
    for (int w = 0; w < NWAVES; ++w) s += red[w];
    atomicAdd(accum, s);
  }
  sbar(cntArr + 800 * 16, GRID);               // global: all partials landed
  if (wg == 0 && tid == 0) out[0] = aloadf(accum) * (1.f / 16384.f);
}

extern "C" void kernel_launch(void* const* d_in, const int* in_sizes, int n_in,
                              void* d_out, int out_size, void* d_ws, size_t ws_size,
                              hipStream_t stream) {
  const float* pcs1 = (const float*)d_in[0];
  const float* pcs2 = (const float*)d_in[1];
  float* out = (float*)d_out;
  char*  base = (char*)d_ws;
  float* fArr   = (float*)base;                    // 64KB
  float* gArr   = (float*)(base + 64 * 1024);      // 64KB
  float* accum  = (float*)(base + 128 * 1024);     // 1 float
  int*   cntArr = (int*)(base + 192 * 1024);       // 801 x 64B
  float4* P1r   = (float4*)(base + 512 * 1024);    // 256KB
  float4* P2r   = (float4*)(base + 768 * 1024);    // 256KB

  pack_pts<<<(2 * BB * NN + 255) / 256, 256, 0, stream>>>(
      pcs1, pcs2, P1r, P2r, cntArr, accum);

  // plain launch (r14: coop API silently no-ops >256 blocks @1024 thr;
  // 256 blocks = 1 WG/CU is trivially co-resident)
  emd_sinkhorn_fused<<<GRID, WGS, 0, stream>>>(
      P1r, P2r, fArr, gArr, cntArr, accum, out);
}